// Round 16
// baseline (3655.819 us; speedup 1.0000x reference)
//
#include <hip/hip_runtime.h>
#include <stdint.h>

// Farthest point sampling, pointops semantics.
// B=8 batches, n=65536, stride=64 -> m=1024 samples/batch.
//
// Round 16 = round 15's proven 1-wave-WG machinery, software-pipelined
// across 2 chains (batches) per WG: per round, compute+publish BOTH
// chains' candidates, THEN poll both. Chain 0's publish->visible latency
// elapses under chain 1's compute; the polls mostly find tags already
// set. Round cost ~= 2*compute + residual discovery, instead of
// 2*(compute + full handshake). (r9 tried this on a barriered/congested
// base and failed; the r15 base is barrier-free with 1-line slot polls.)
//
// Geometry: grid 256, active WGs = those with (bg&7)<4 (128 WGs).
// pair = bg&7 (0..3), g = bg>>3 (0..31). Under the CP's round-robin
// XCD assignment (validated r10/r13/r15 via FETCH collapse), a pair's
// 32 WGs all land on XCD 'pair' (32 CUs/XCD) -> sc0 handshake stays
// XCD-L2-local. Correctness NEVER depends on this: the same-iteration
// sc0->sc1 dual-probe poll (r13/r15, with "memory" clobbers -- r14's
// missing clobber let the sc0 load get hoisted, lesson learned) makes
// progress in the device domain regardless of placement.
//
// Per chain, the sync scheme is byte-identical to r15: self-contained
// packed key (it|dist_bits|0xFFFF-idx), parity-double-buffered cells,
// monotone tags, dual-domain publish. Round-7 induction per chain:
// publish(c,it+2) by wave s follows its poll(c,it+1), which requires
// every wave published (c,it+1), which follows their poll(c,it) in wave
// program order => no reader of (c,it) sees the it+2 overwrite, no
// deadlock. comm memset every launch -> graph-replay deterministic.

#define G      32    // WGs (waves) per batch == slots per batch
#define BS     64    // threads per WG = 1 wave
#define PPT    32    // points per thread per chain (G*BS*PPT == n)
#define NC     8     // float4 chunks per thread per chain
#define CH     2     // chains (batches) per WG
#define NBATCH 8

typedef unsigned long long u64;
typedef unsigned int u32;

// key layout: [63:48]=it  [47:16]=float bits of best dist (nonneg)
//             [15:0]=0xFFFF-idx  (bigger wins => smaller idx wins ties,
//             numpy argmax first-max semantics; nonneg IEEE floats
//             compare like their bit patterns)

__device__ inline u64 ld_sc0(const u64* a) {
    u64 v;
    asm volatile("global_load_dwordx2 %0, %1, off sc0\n\t"
                 "s_waitcnt vmcnt(0)"
                 : "=v"(v) : "v"(a) : "memory");
    return v;
}
__device__ inline void st_sc0(u64* a, u64 v) {
    asm volatile("global_store_dwordx2 %0, %1, off sc0"
                 :: "v"(a), "v"(v) : "memory");
}

__global__ __launch_bounds__(BS, 1)
void fps_pipe(const float* __restrict__ p, int n, int m,
              u64* __restrict__ comm,
              float* __restrict__ out_np, float* __restrict__ out_no,
              float* __restrict__ out_idx)
{
#pragma clang fp contract(off)
    const int bg = blockIdx.x;
    if ((bg & 7) >= 4) return;           // 128 active WGs (XCDs 0..3)
    const int pair = bg & 7;             // 0..3, co-XCD group
    const int g    = bg >> 3;            // 0..31 within pair
    const int t    = threadIdx.x;        // == lane

    // chain c serves batch 2*pair + c
    int   gbase[CH];
    u64*  cb[CH];
#pragma unroll
    for (int c = 0; c < CH; ++c) {
        int b = 2 * pair + c;
        gbase[c] = b * n;
        cb[c] = comm + (size_t)b * 128;  // r15 layout: sc0 par*32 | 64+par*32
    }
    const int tloc = g * (BS * PPT) + t * PPT;   // batch-local thread base

    __shared__ float4 xs[CH][NC * BS], ys[CH][NC * BS], zs[CH][NC * BS]; // 48KB

    // ---- stage both chains' 32 pts/thread into LDS (one-time) ----
#pragma unroll
    for (int c = 0; c < CH; ++c) {
        const float4* pb = (const float4*)(p + 3ull * (u32)(gbase[c] + tloc));
#pragma unroll
        for (int h = 0; h < 2; ++h) {
            float cf[48];
#pragma unroll
            for (int v = 0; v < 12; ++v) {
                float4 f = pb[h * 12 + v];
                cf[4 * v + 0] = f.x; cf[4 * v + 1] = f.y;
                cf[4 * v + 2] = f.z; cf[4 * v + 3] = f.w;
            }
#pragma unroll
            for (int cc = 0; cc < 4; ++cc) {
                int ch = h * 4 + cc;
                xs[c][ch * BS + t] = make_float4(cf[(cc * 4 + 0) * 3 + 0],
                                                 cf[(cc * 4 + 1) * 3 + 0],
                                                 cf[(cc * 4 + 2) * 3 + 0],
                                                 cf[(cc * 4 + 3) * 3 + 0]);
                ys[c][ch * BS + t] = make_float4(cf[(cc * 4 + 0) * 3 + 1],
                                                 cf[(cc * 4 + 1) * 3 + 1],
                                                 cf[(cc * 4 + 2) * 3 + 1],
                                                 cf[(cc * 4 + 3) * 3 + 1]);
                zs[c][ch * BS + t] = make_float4(cf[(cc * 4 + 0) * 3 + 2],
                                                 cf[(cc * 4 + 1) * 3 + 2],
                                                 cf[(cc * 4 + 2) * 3 + 2],
                                                 cf[(cc * 4 + 3) * 3 + 2]);
            }
        }
    }
    __syncthreads();   // LDS ready; never written again

    float dist0[PPT], dist1[PPT];
#pragma unroll
    for (int j = 0; j < PPT; ++j) { dist0[j] = 1e10f; dist1[j] = 1e10f; }

    // first query of each chain = point 0 of its batch
    float qx[CH], qy[CH], qz[CH];
#pragma unroll
    for (int c = 0; c < CH; ++c) {
        const float* q0 = p + 3ull * (u32)gbase[c];
        qx[c] = q0[0]; qy[c] = q0[1]; qz[c] = q0[2];
    }
    if (g == 0 && t == 0) {
#pragma unroll
        for (int c = 0; c < CH; ++c) {
            int b = 2 * pair + c;
            out_idx[(size_t)b * m] = (float)gbase[c];
            out_np[(size_t)(b * m) * 3 + 0] = qx[c];
            out_np[(size_t)(b * m) * 3 + 1] = qy[c];
            out_np[(size_t)(b * m) * 3 + 2] = qz[c];
            out_no[b] = (float)((b + 1) * m);
        }
    }

    for (int it = 1; it < m; ++it) {
        const int par = it & 1;

        // ================= compute + publish, chain 0 then chain 1 ========
#pragma unroll
        for (int c = 0; c < CH; ++c) {
            float* dist = (c == 0) ? dist0 : dist1;
            float best = -1.0f;
            int   bj   = 0;
#pragma unroll
            for (int cc = 0; cc < NC; ++cc) {
                float4 X = xs[c][cc * BS + t];
                float4 Y = ys[c][cc * BS + t];
                float4 Z = zs[c][cc * BS + t];
                float xl[4] = {X.x, X.y, X.z, X.w};
                float yl[4] = {Y.x, Y.y, Y.z, Y.w};
                float zl[4] = {Z.x, Z.y, Z.z, Z.w};
#pragma unroll
                for (int e = 0; e < 4; ++e) {
                    float dx = xl[e] - qx[c];
                    float dy = yl[e] - qy[c];
                    float dz = zl[e] - qz[c];
                    float d  = dx * dx + dy * dy + dz * dz; // contract off
                    int j = cc * 4 + e;
                    float nd = fminf(dist[j], d);
                    dist[j] = nd;
                    if (nd > best) { best = nd; bj = j; }   // strict >: earliest
                }
            }
            int bidx = tloc + bj;    // batch-local winner idx (ascends w/ lane)

            float v = best;
#pragma unroll
            for (int off = 1; off < 64; off <<= 1)
                v = fmaxf(v, __shfl_xor(v, off));
            u64 msk = __ballot(best == v);
            int src = __ffsll((unsigned long long)msk) - 1;
            int widx = __shfl(bidx, src);   // smallest idx among maxima

            if (t == 0) {
                u64 kk = ((u64)(u32)it << 48)
                       | ((u64)(u32)__float_as_uint(v) << 16)
                       | (u64)(u32)(0xFFFF - widx);
                u64* sb0 = cb[c] + (size_t)par * G;
                u64* sb1 = cb[c] + 2 * G + (size_t)par * G;
                st_sc0(sb0 + g, kk);
                __hip_atomic_store(sb1 + g, kk, __ATOMIC_RELAXED,
                                   __HIP_MEMORY_SCOPE_AGENT);
            }
        }

        // ================= poll + reduce + q-load, chain 0 then 1 =========
#pragma unroll
        for (int c = 0; c < CH; ++c) {
            u64* sb0 = cb[c] + (size_t)par * G;
            u64* sb1 = cb[c] + 2 * G + (size_t)par * G;

            u64 k = 0;
            bool ok;
            do {
                ok = true;
                if (t < G) {
                    k = ld_sc0(sb0 + t);
                    if ((u32)(k >> 48) != (u32)it) {
                        k = __hip_atomic_load(sb1 + t, __ATOMIC_RELAXED,
                                              __HIP_MEMORY_SCOPE_AGENT);
                    }
                    ok = ((u32)(k >> 48) == (u32)it);
                } else {
                    k = 0;   // upper lanes: never win the key-max
                }
            } while (!__all(ok));

#pragma unroll
            for (int off = 1; off < 64; off <<= 1) {
                u64 k2 = __shfl_xor(k, off);
                if (k2 > k) k = k2;
            }
            int kidx = 0xFFFF - (int)(k & 0xFFFF);

            const float* wp = p + 3ull * (u32)(gbase[c] + kidx);
            qx[c] = wp[0]; qy[c] = wp[1]; qz[c] = wp[2];

            // rotated writer (r15): no fixed straggler wave
            if (g == (it & (G - 1)) && t == 0) {
                int b = 2 * pair + c;
                out_idx[(size_t)b * m + it] = (float)(gbase[c] + kidx);
                out_np[(size_t)(b * m + it) * 3 + 0] = qx[c];
                out_np[(size_t)(b * m + it) * 3 + 1] = qy[c];
                out_np[(size_t)(b * m + it) * 3 + 2] = qz[c];
            }
        }
    }
}

extern "C" void kernel_launch(void* const* d_in, const int* in_sizes, int n_in,
                              void* d_out, int out_size, void* d_ws, size_t ws_size,
                              hipStream_t stream) {
    const float* p = (const float*)d_in[0];
    int N = in_sizes[0] / 3;           // 524288
    int B = in_sizes[1];               // 8
    int n = N / B;                     // 65536
    int m = (out_size / B - 1) / 4;    // 1024

    float* out_np  = (float*)d_out;
    float* out_no  = out_np + (size_t)B * m * 3;
    float* out_idx = out_no + B;

    u64* comm = (u64*)d_ws;
    // clear all slot cells (both domains, both parities) every launch
    hipMemsetAsync(d_ws, 0, (size_t)NBATCH * 128 * sizeof(u64), stream);

    fps_pipe<<<256, BS, 0, stream>>>(p, n, m, comm,
                                     out_np, out_no, out_idx);
}

// Round 17
// 2881.300 us; speedup vs baseline: 1.2688x; 1.2688x over previous
//
#include <hip/hip_runtime.h>
#include <stdint.h>

// Farthest point sampling, pointops semantics.
// B=8 batches, n=65536, stride=64 -> m=1024 samples/batch.
//
// Round 17 = round 15 (best: 2.0ms) with ONE change: the sc1 (device-
// domain) fallback probe in the poll loop fires only every 8th failing
// iteration instead of every iteration. The sc0 probe (~250cy, XCD-L2)
// is proven live (r10/r13 FETCH collapse; all asm carries "memory"
// clobbers -- r14's regression was a missing clobber letting the sc0
// load hoist out of the loop, not a flaw in cadenced fallback). sc1 is
// still probed infinitely often => guaranteed progress, deadlock-free,
// no budget/sticky state. Steady-state poll iteration cost drops
// ~950cy -> ~250cy, removing most of the discovery latency.
//
// Everything else identical to r15: 1-wave WGs (64 thr), 32 WGs/batch,
// 32 pts/thread in LDS float4-transposed, zero barriers in the loop,
// ballot argmax, dual-domain publish (sc0+sc1), packed self-contained
// keys (it|dist_bits|0xFFFF-idx), parity-double-buffered cells with
// monotone tags, hoisted coord reloads under the poll, rotated writer.
//
// Correctness: keys are 8B single-copy-atomic and self-contained;
// round-7 induction: slot s's parity cell for step it is overwritten
// only by publish(it+2) from wave s, which follows wave s's poll(it+1),
// which requires EVERY wave published (it+1), which each does only
// after completing poll(it) in wave program order. Both domain copies
// carry identical payloads; stale tags lose the u64 max automatically.
// comm memset every launch -> graph-replay deterministic.

#define G      32    // workgroups (waves) per batch == slots per batch
#define BS     64    // threads per workgroup = 1 wave
#define PPT    32    // points per thread (G*BS*PPT == n)
#define NC     8     // float4 chunks per thread
#define NBATCH 8

typedef unsigned long long u64;
typedef unsigned int u32;

// key layout: [63:48]=it  [47:16]=float bits of best dist (nonneg)
//             [15:0]=0xFFFF-idx  (bigger wins => smaller idx wins ties,
//             numpy argmax first-max semantics; nonneg IEEE floats
//             compare like their bit patterns)

__device__ inline u64 ld_sc0(const u64* a) {
    u64 v;
    asm volatile("global_load_dwordx2 %0, %1, off sc0\n\t"
                 "s_waitcnt vmcnt(0)"
                 : "=v"(v) : "v"(a) : "memory");
    return v;
}
__device__ inline void st_sc0(u64* a, u64 v) {
    asm volatile("global_store_dwordx2 %0, %1, off sc0"
                 :: "v"(a), "v"(v) : "memory");
}

__global__ __launch_bounds__(BS, 1)
void fps_r17(const float* __restrict__ p, int n, int m,
             u64* __restrict__ comm,
             float* __restrict__ out_np, float* __restrict__ out_no,
             float* __restrict__ out_idx)
{
#pragma clang fp contract(off)
    const int bg   = blockIdx.x;
    const int b    = bg & (NBATCH - 1);  // %8: co-XCD under round-robin CP
    const int g    = bg >> 3;            // 0..31 within batch
    const int t    = threadIdx.x;        // == lane
    const int gbase = b * n;
    const int tbase = g * (BS * PPT) + t * PPT;  // batch-local thread base

    __shared__ float4 xs[NC * BS], ys[NC * BS], zs[NC * BS];  // 24 KB

    // ---- stage 32 pts/thread into LDS, float4-transposed (one-time) ----
    {
        const float4* pb = (const float4*)(p + 3ull * (u32)(gbase + tbase));
#pragma unroll
        for (int h = 0; h < 2; ++h) {
            float c[48];
#pragma unroll
            for (int v = 0; v < 12; ++v) {
                float4 f = pb[h * 12 + v];
                c[4 * v + 0] = f.x; c[4 * v + 1] = f.y;
                c[4 * v + 2] = f.z; c[4 * v + 3] = f.w;
            }
#pragma unroll
            for (int cc = 0; cc < 4; ++cc) {
                int ch = h * 4 + cc;
                xs[ch * BS + t] = make_float4(c[(cc * 4 + 0) * 3 + 0],
                                              c[(cc * 4 + 1) * 3 + 0],
                                              c[(cc * 4 + 2) * 3 + 0],
                                              c[(cc * 4 + 3) * 3 + 0]);
                ys[ch * BS + t] = make_float4(c[(cc * 4 + 0) * 3 + 1],
                                              c[(cc * 4 + 1) * 3 + 1],
                                              c[(cc * 4 + 2) * 3 + 1],
                                              c[(cc * 4 + 3) * 3 + 1]);
                zs[ch * BS + t] = make_float4(c[(cc * 4 + 0) * 3 + 2],
                                              c[(cc * 4 + 1) * 3 + 2],
                                              c[(cc * 4 + 2) * 3 + 2],
                                              c[(cc * 4 + 3) * 3 + 2]);
            }
        }
    }
    __syncthreads();   // LDS ready; never written again

    float dist[PPT];
#pragma unroll
    for (int j = 0; j < PPT; ++j) dist[j] = 1e10f;

    // coord working set for the upcoming step (hoisted loads)
    float4 CX[NC], CY[NC], CZ[NC];
#pragma unroll
    for (int cc = 0; cc < NC; ++cc) {
        CX[cc] = xs[cc * BS + t];
        CY[cc] = ys[cc * BS + t];
        CZ[cc] = zs[cc * BS + t];
    }

    // first query = point 0 of the batch
    float qx = p[3ull * (u32)gbase + 0];
    float qy = p[3ull * (u32)gbase + 1];
    float qz = p[3ull * (u32)gbase + 2];

    if (g == 0 && t == 0) {
        out_idx[(size_t)b * m] = (float)gbase;
        out_np[(size_t)(b * m) * 3 + 0] = qx;
        out_np[(size_t)(b * m) * 3 + 1] = qy;
        out_np[(size_t)(b * m) * 3 + 2] = qz;
        out_no[b] = (float)((b + 1) * m);
    }

    // per-batch comm (1 KB): sc0 cells [par*32], sc1 cells [64 + par*32]
    u64* cb = comm + (size_t)b * 128;

    for (int it = 1; it < m; ++it) {
        // ---- local distance update + per-thread argmax (ids ascend in j) ----
        float best = -1.0f;
        int   bj   = 0;
#pragma unroll
        for (int cc = 0; cc < NC; ++cc) {
            float xl[4] = {CX[cc].x, CX[cc].y, CX[cc].z, CX[cc].w};
            float yl[4] = {CY[cc].x, CY[cc].y, CY[cc].z, CY[cc].w};
            float zl[4] = {CZ[cc].x, CZ[cc].y, CZ[cc].z, CZ[cc].w};
#pragma unroll
            for (int e = 0; e < 4; ++e) {
                float dx = xl[e] - qx;
                float dy = yl[e] - qy;
                float dz = zl[e] - qz;
                float d  = dx * dx + dy * dy + dz * dz;  // contract off
                int j = cc * 4 + e;
                float nd = fminf(dist[j], d);
                dist[j] = nd;
                if (nd > best) { best = nd; bj = j; }    // strict >: earliest j
            }
        }
        int bidx = tbase + bj;   // batch-local winner idx (ascends with lane)

        // ---- ballot wave argmax: max butterfly + first-max lane pick ----
        float v = best;
#pragma unroll
        for (int off = 1; off < 64; off <<= 1)
            v = fmaxf(v, __shfl_xor(v, off));
        u64 msk = __ballot(best == v);
        int src = __ffsll((unsigned long long)msk) - 1;
        int widx = __shfl(bidx, src);    // smallest idx among maxima

        u64* sb0 = cb + (size_t)(it & 1) * G;          // sc0 cells (2 lines)
        u64* sb1 = cb + 2 * G + (size_t)(it & 1) * G;  // sc1 mirrors

        // ---- lane 0: dual publish of this wave's self-contained key ----
        if (t == 0) {
            u64 kk = ((u64)(u32)it << 48)
                   | ((u64)(u32)__float_as_uint(v) << 16)
                   | (u64)(u32)(0xFFFF - widx);
            st_sc0(sb0 + g, kk);
            __hip_atomic_store(sb1 + g, kk, __ATOMIC_RELAXED,
                               __HIP_MEMORY_SCOPE_AGENT);
        }

        // ---- hoisted coord loads for step it+1: lgkm latency completes
        //      under the vm-poll below ("memory"-clobbered asm pins them) ----
#pragma unroll
        for (int cc = 0; cc < NC; ++cc) {
            CX[cc] = xs[cc * BS + t];
            CY[cc] = ys[cc * BS + t];
            CZ[cc] = zs[cc * BS + t];
        }

        // ---- all lanes: poll. sc0 every iteration (proven-live probe);
        //      sc1 fallback only every 8th failing iteration (insurance,
        //      probed infinitely often => deadlock-free) ----
        u64 k = 0;
        int  iter = 0;
        bool ok;
        do {
            ok = true;
            if (t < G) {
                k = ld_sc0(sb0 + t);
                if ((u32)(k >> 48) != (u32)it && (iter & 7) == 7) {
                    u64 k1 = __hip_atomic_load(sb1 + t, __ATOMIC_RELAXED,
                                               __HIP_MEMORY_SCOPE_AGENT);
                    if ((u32)(k1 >> 48) == (u32)it) k = k1;
                }
                ok = ((u32)(k >> 48) == (u32)it);
            } else {
                k = 0;   // upper lanes: never win the key-max
            }
            ++iter;
        } while (!__all(ok));

        // ---- key-max butterfly over 64 lanes (upper 32 carry 0) ----
#pragma unroll
        for (int off = 1; off < 64; off <<= 1) {
            u64 k2 = __shfl_xor(k, off);
            if (k2 > k) k = k2;
        }
        int kidx = 0xFFFF - (int)(k & 0xFFFF);

        // winner coords from read-only p (L2-warm; no cache-inv in loop)
        const float* wp = p + 3ull * (u32)(gbase + kidx);
        qx = wp[0]; qy = wp[1]; qz = wp[2];

        // rotated writer: no fixed straggler wave
        if (g == (it & (G - 1)) && t == 0) {
            out_idx[(size_t)b * m + it] = (float)(gbase + kidx);
            out_np[(size_t)(b * m + it) * 3 + 0] = qx;
            out_np[(size_t)(b * m + it) * 3 + 1] = qy;
            out_np[(size_t)(b * m + it) * 3 + 2] = qz;
        }
    }
}

extern "C" void kernel_launch(void* const* d_in, const int* in_sizes, int n_in,
                              void* d_out, int out_size, void* d_ws, size_t ws_size,
                              hipStream_t stream) {
    const float* p = (const float*)d_in[0];
    int N = in_sizes[0] / 3;           // 524288
    int B = in_sizes[1];               // 8
    int n = N / B;                     // 65536
    int m = (out_size / B - 1) / 4;    // 1024

    float* out_np  = (float*)d_out;
    float* out_no  = out_np + (size_t)B * m * 3;
    float* out_idx = out_no + B;

    u64* comm = (u64*)d_ws;
    // clear all slot cells (both domains, both parities) every launch
    hipMemsetAsync(d_ws, 0, (size_t)NBATCH * 128 * sizeof(u64), stream);

    fps_r17<<<NBATCH * G, BS, 0, stream>>>(p, n, m, comm,
                                           out_np, out_no, out_idx);
}